// Round 13
// baseline (620.536 us; speedup 1.0000x reference)
//
#include <hip/hip_runtime.h>
#include <hip/hip_bf16.h>
#include <stdint.h>

#define NR 16384
#define DIM 512
#define BM 128
#define BN 128
#define BK 32
#define NKT (DIM / BK)     // 16 K-tiles
#define NTILE (NR / BM)    // 128 tile rows/cols

typedef __bf16 bf16x8 __attribute__((ext_vector_type(8)));
typedef float f32x4 __attribute__((ext_vector_type(4)));

__device__ inline ushort f2bf(float x) {
  uint32_t u = __float_as_uint(x);
  uint32_t r = (u + 0x7FFFu + ((u >> 16) & 1u)) >> 16;
  return (ushort)r;
}

// Kernel 1: fp32 -> bf16 (RNE) for both matrices + fused diagonal dot.
__global__ __launch_bounds__(256) void convert_diag(
    const float* __restrict__ I, const float* __restrict__ T,
    const float* __restrict__ scale_p,
    ushort* __restrict__ bI, ushort* __restrict__ bT,
    float* __restrict__ diag)
{
  int wid = threadIdx.x >> 6;
  int lane = threadIdx.x & 63;
  int row = blockIdx.x * 4 + wid;
  const float4* I4 = (const float4*)(I + (size_t)row * DIM);
  const float4* T4 = (const float4*)(T + (size_t)row * DIM);
  ushort* bIr = bI + (size_t)row * DIM;
  ushort* bTr = bT + (size_t)row * DIM;
  float dot = 0.f;
#pragma unroll
  for (int h = 0; h < 2; ++h) {
    int idx = lane + h * 64;
    float4 a = I4[idx];
    float4 b = T4[idx];
    dot += a.x * b.x + a.y * b.y + a.z * b.z + a.w * b.w;
    ushort4 ha, hb;
    ha.x = f2bf(a.x); ha.y = f2bf(a.y); ha.z = f2bf(a.z); ha.w = f2bf(a.w);
    hb.x = f2bf(b.x); hb.y = f2bf(b.y); hb.z = f2bf(b.z); hb.w = f2bf(b.w);
    *(ushort4*)(bIr + (size_t)idx * 4) = ha;
    *(ushort4*)(bTr + (size_t)idx * 4) = hb;
  }
#pragma unroll
  for (int off = 32; off > 0; off >>= 1) dot += __shfl_down(dot, off);
  if (lane == 0) diag[row] = scale_p[0] * dot;
}

// Kernel 2: m97-structure 128x128 bf16 MFMA GEMM (4 waves 2x2, BK=32,
// double-buffered global_load_lds, plain __syncthreads -> multi-block/CU
// overlap absorbs barrier drain, per m114). Two proven grafts:
//  - bi-fast bijective XCD map (R4: FETCH 1.06GB -> 74MB),
//  - both-sides XOR bank swizzle (write src slot (tid&3)^((tid>>2)&3),
//    read phys slot (lane>>4)^(lane&3); residual 2-way = free).
// Fused per-tile row/col LSE partials in epilogue.
__global__ __launch_bounds__(256) void gemm_lse(
    const ushort* __restrict__ bI, const ushort* __restrict__ bT,
    const float* __restrict__ scale_p,
    float2* __restrict__ rowPart, float2* __restrict__ colPart)
{
  __shared__ __align__(16) ushort As[2][BM * BK];
  __shared__ __align__(16) ushort Bs[2][BN * BK];
  __shared__ float2 redRow[BM][2];
  __shared__ float2 redCol[BN][2];

  // XCD map: XCD x owns a 16(bi) x 128(bj) slab, bi FAST.
  // A-slab (16 panels, 2 MB) stays L2-resident; B panels stream.
  int bid = blockIdx.x;
  int x = bid & 7, s = bid >> 3;        // nwg = 16384, %8==0 -> bijective
  int bi = x * 16 + (s & 15);           // 0..127
  int bj = s >> 4;                      // 0..127

  int tid = threadIdx.x;
  int w = tid >> 6, lane = tid & 63;
  int wr = w >> 1, wc = w & 1;          // 2x2 wave grid, 64x64 per wave

  f32x4 acc[4][4];
#pragma unroll
  for (int m = 0; m < 4; ++m)
#pragma unroll
    for (int n = 0; n < 4; ++n)
      acc[m][n] = (f32x4){0.f, 0.f, 0.f, 0.f};

  int r4 = lane >> 2;                   // row within 16-row chunk
  // source col-slot pre-swizzled: logical slot (tid&3)^g(row), g(r)=r&3;
  // row within chunk = lane>>2 and chunk*16 == 0 (mod 4), so g = (lane>>2)&3.
  int c8 = ((lane & 3) ^ ((lane >> 2) & 3)) * 8;

  auto stage = [&](int buf, int kt) {
#pragma unroll
    for (int L = 0; L < 2; ++L) {
      int c = L * 4 + w;                // chunk 0..7, 16 rows each
      const ushort* gA = bI + ((size_t)(bi * BM + c * 16 + r4) * DIM + kt * BK + c8);
      __builtin_amdgcn_global_load_lds(
          (const __attribute__((address_space(1))) void*)gA,
          (__attribute__((address_space(3))) void*)&As[buf][c * 16 * BK], 16, 0, 0);
      const ushort* gB = bT + ((size_t)(bj * BN + c * 16 + r4) * DIM + kt * BK + c8);
      __builtin_amdgcn_global_load_lds(
          (const __attribute__((address_space(1))) void*)gB,
          (__attribute__((address_space(3))) void*)&Bs[buf][c * 16 * BK], 16, 0, 0);
    }
  };

  stage(0, 0);
  __syncthreads();

  // read-side swizzle: phys slot = (lane>>4) ^ (row&3); row&3 == lane&3.
  int sphys = (((lane >> 4) ^ (lane & 3)) << 4);   // byte offset of 16B slot

  int buf = 0;
  for (int kt = 0; kt < NKT; ++kt) {
    if (kt + 1 < NKT) stage(buf ^ 1, kt + 1);
    int aRow = wr * 64 + (lane & 15);
    int bRow = wc * 64 + (lane & 15);
    bf16x8 aF[4], bF[4];
#pragma unroll
    for (int m = 0; m < 4; ++m)
      aF[m] = *(const bf16x8*)((const char*)&As[buf][0] + (aRow + m * 16) * (BK * 2) + sphys);
#pragma unroll
    for (int n = 0; n < 4; ++n)
      bF[n] = *(const bf16x8*)((const char*)&Bs[buf][0] + (bRow + n * 16) * (BK * 2) + sphys);
#pragma unroll
    for (int m = 0; m < 4; ++m)
#pragma unroll
      for (int n = 0; n < 4; ++n)
        acc[m][n] = __builtin_amdgcn_mfma_f32_16x16x32_bf16(aF[m], bF[n], acc[m][n], 0, 0, 0);
    __syncthreads();
    buf ^= 1;
  }

  // ---- epilogue: scale, then per-tile row/col (max, sumexp) partials ----
  float sc = scale_p[0];
#pragma unroll
  for (int m = 0; m < 4; ++m)
#pragma unroll
    for (int n = 0; n < 4; ++n)
      acc[m][n] = acc[m][n] * sc;

  // C/D layout (m89-verified): col = lane&15, row = (lane>>4)*4 + reg.
#pragma unroll
  for (int m = 0; m < 4; ++m) {
#pragma unroll
    for (int j = 0; j < 4; ++j) {
      float rm = fmaxf(fmaxf(acc[m][0][j], acc[m][1][j]),
                       fmaxf(acc[m][2][j], acc[m][3][j]));
#pragma unroll
      for (int msk = 1; msk <= 8; msk <<= 1) rm = fmaxf(rm, __shfl_xor(rm, msk));
      float rs = 0.f;
#pragma unroll
      for (int n = 0; n < 4; ++n) rs += __expf(acc[m][n][j] - rm);
#pragma unroll
      for (int msk = 1; msk <= 8; msk <<= 1) rs += __shfl_xor(rs, msk);
      if ((lane & 15) == 0) {
        int r = wr * 64 + m * 16 + (lane >> 4) * 4 + j;
        redRow[r][wc] = make_float2(rm, rs);
      }
    }
  }
#pragma unroll
  for (int n = 0; n < 4; ++n) {
    float cm = -1e30f;
#pragma unroll
    for (int m = 0; m < 4; ++m)
#pragma unroll
      for (int j = 0; j < 4; ++j) cm = fmaxf(cm, acc[m][n][j]);
    cm = fmaxf(cm, __shfl_xor(cm, 16));
    cm = fmaxf(cm, __shfl_xor(cm, 32));
    float csum = 0.f;
#pragma unroll
    for (int m = 0; m < 4; ++m)
#pragma unroll
      for (int j = 0; j < 4; ++j) csum += __expf(acc[m][n][j] - cm);
    csum += __shfl_xor(csum, 16);
    csum += __shfl_xor(csum, 32);
    if (lane < 16) {
      int cidx = wc * 64 + n * 16 + lane;
      redCol[cidx][wr] = make_float2(cm, csum);
    }
  }
  __syncthreads();

  if (tid < BM) {
    float2 p0 = redRow[tid][0], p1 = redRow[tid][1];
    float m_ = fmaxf(p0.x, p1.x);
    float s_ = p0.y * __expf(p0.x - m_) + p1.y * __expf(p1.x - m_);
    rowPart[(size_t)bj * NR + bi * BM + tid] = make_float2(m_, s_);
  } else {
    int t = tid - BM;
    float2 p0 = redCol[t][0], p1 = redCol[t][1];
    float m_ = fmaxf(p0.x, p1.x);
    float s_ = p0.y * __expf(p0.x - m_) + p1.y * __expf(p1.x - m_);
    colPart[(size_t)bi * NR + bj * BN + t] = make_float2(m_, s_);
  }
}

// Kernel 3: merge 128 partials per row/col, subtract diag, accumulate mean.
__global__ __launch_bounds__(256) void reduce_final(
    const float2* __restrict__ rowPart, const float2* __restrict__ colPart,
    const float* __restrict__ diag, float* __restrict__ out)
{
  int bid = blockIdx.x;            // 0..127; first 64 rows, last 64 cols
  bool isCol = bid >= 64;
  int i = (bid & 63) * 256 + threadIdx.x;
  const float2* part = isCol ? colPart : rowPart;
  float m = -1e30f, s = 0.f;
  for (int b = 0; b < NTILE; ++b) {
    float2 p = part[(size_t)b * NR + i];
    float mn = fmaxf(m, p.x);
    s = s * __expf(m - mn) + p.y * __expf(p.x - mn);
    m = mn;
  }
  float contrib = (m + __logf(s)) - diag[i];
#pragma unroll
  for (int off = 32; off > 0; off >>= 1) contrib += __shfl_down(contrib, off);
  __shared__ float wsum[4];
  int wid = threadIdx.x >> 6, lane = threadIdx.x & 63;
  if (lane == 0) wsum[wid] = contrib;
  __syncthreads();
  if (threadIdx.x == 0) {
    float tot = wsum[0] + wsum[1] + wsum[2] + wsum[3];
    atomicAdd(out, tot * (1.0f / (2.0f * NR)));
  }
}

extern "C" void kernel_launch(void* const* d_in, const int* in_sizes, int n_in,
                              void* d_out, int out_size, void* d_ws, size_t ws_size,
                              hipStream_t stream) {
  const float* I = (const float*)d_in[0];
  const float* T = (const float*)d_in[1];
  const float* scale = (const float*)d_in[2];
  float* out = (float*)d_out;

  char* ws = (char*)d_ws;
  ushort* bI      = (ushort*)(ws);                          // 16 MB
  ushort* bT      = (ushort*)(ws + ((size_t)16 << 20));     // 16 MB
  float2* rowPart = (float2*)(ws + ((size_t)32 << 20));     // 16 MB
  float2* colPart = (float2*)(ws + ((size_t)48 << 20));     // 16 MB
  float*  diag    = (float*) (ws + ((size_t)64 << 20));     // 64 KB

  hipMemsetAsync(d_out, 0, sizeof(float), stream);
  convert_diag<<<NR / 4, 256, 0, stream>>>(I, T, scale, bI, bT, diag);
  gemm_lse<<<NTILE * NTILE, 256, 0, stream>>>(bI, bT, scale, rowPart, colPart);
  reduce_final<<<128, 256, 0, stream>>>(rowPart, colPart, diag, out);
}